// Round 1
// baseline (95.416 us; speedup 1.0000x reference)
//
#include <hip/hip_runtime.h>

#define IN_F 8192
#define OUT_F 8192
#define BATCH 64
#define TQ 64                   // output columns per tile
#define NTILE (OUT_F / TQ)      // 128 tiles
#define ROWS 16                 // batch rows per block (grid.y = 4)
#define CH 64                   // entries per weight-tile chunk
#define CAP 512                 // per-tile list capacity (expected ~166, max ~224)
#define PASS 2048               // (fallback kernel only)

// ---- workspace layout ----
#define XT_BYTES   ((size_t)IN_F * BATCH * sizeof(float))        // 2 MiB
#define CNT_OFF    XT_BYTES                                      // 128 ints
#define LIST_OFF   (XT_BYTES + 1024)                             // 16B-aligned
#define LIST_BYTES ((size_t)NTILE * CAP * sizeof(float4))        // 1 MiB
#define WS_NEEDED  (LIST_OFF + LIST_BYTES)

// ---------------- Kernel 1: prep = transpose x  +  scatter-bin features ----------------
// blocks 0..127  : transpose x [64,8192] -> xT [8192,64]
// blocks 128..159: each thread bins one feature into the per-tile lists (global atomics).
__global__ __launch_bounds__(256) void prep_kern(
    const float* __restrict__ x, const float* __restrict__ mu,
    const float* __restrict__ sigma, const float* __restrict__ amp,
    float* __restrict__ xT, int* __restrict__ cnt, float4* __restrict__ list) {
    const int tid = threadIdx.x;
    if (blockIdx.x < NTILE) {
        __shared__ float tile[64][65];   // +1 pad: conflict-free
        const int i0 = blockIdx.x * 64;
#pragma unroll
        for (int u = tid; u < 64 * 64; u += 256) {
            const int b = u >> 6;
            const int i = u & 63;          // fastest -> coalesced reads
            tile[i][b] = x[b * IN_F + i0 + i];
        }
        __syncthreads();
#pragma unroll
        for (int u = tid; u < 64 * 64; u += 256) {
            const int i = u >> 6;
            const int b = u & 63;          // fastest -> coalesced writes
            xT[(i0 + i) * 64 + b] = tile[i][b];
        }
    } else {
        const int i = (blockIdx.x - NTILE) * 256 + tid;   // 32 blocks * 256 = 8192
        const float m = mu[i];
        const float s = sigma[i];
        // R = 5σ+1: dropped-tail absmax ~3e-5 << threshold
        const float R = 5.0f * fabsf(s) + 1.0f;
        // tile kept iff m in [64t - R, 64t + 63 + R]  (same inclusion as the scan test)
        int t0 = (int)ceilf((m - R - 63.0f) * (1.0f / 64.0f));
        int t1 = (int)floorf((m + R) * (1.0f / 64.0f));
        t0 = max(t0, 0);
        t1 = min(t1, NTILE - 1);
        const float4 e = make_float4(m, -0.72134752f / (s * s), amp[i],
                                     __int_as_float(i));
        for (int t = t0; t <= t1; ++t) {
            const int p = atomicAdd(&cnt[t], 1);
            if (p < CAP) list[(size_t)t * CAP + p] = e;  // expected ~166 << CAP
        }
    }
}

// ---------------- Kernel 2: banded Gaussian FC (list-driven, single pass) ----------------
// grid = (128, 4) = 512 blocks -> 2 blocks/CU. LDS 56 KB/block (2 fit).
// Phase 0: burst-load list (coalesced) + gather ALL x rows (independent float4 loads).
// Then per 64-entry chunk: wtile exps (LDS-only inputs) -> barrier -> pure-FMA -> barrier.
__global__ __launch_bounds__(256, 2) void gauss_main(
    const float4* __restrict__ list, const int* __restrict__ cnt,
    const float* __restrict__ xT, const float* __restrict__ bias,
    float* __restrict__ out) {

    __shared__ float4 lstage[CAP];       // {mu, kl, amp, idx_bits}   8 KB
    __shared__ float  xall[CAP][ROWS];   // x per (entry, row)       32 KB
    __shared__ float  wtile[CH][64];     // weights per (entry, col) 16 KB

    const int tid = threadIdx.x;
    const int cc = (tid & 31) << 1;      // col-pair base: 0,2,...,62
    const int g = tid >> 5;              // 0..7
    const int g2 = g << 1;
    const int t = blockIdx.x;
    const int tile0 = t * TQ;
    const int row0 = blockIdx.y * ROWS;
    const int n = min(cnt[t], CAP);
    const float4* lp = list + (size_t)t * CAP;

    // ---- phase 0: stage list (one coalesced burst) ----
    for (int q = tid; q < n; q += 256) lstage[q] = lp[q];
    __syncthreads();                      // lstage ready (needed for gather indices)

    // gather all x rows for this tile: 4 threads/entry, 16B each, independent loads
    for (int u = tid; u < (n << 2); u += 256) {
        const int ci = u >> 2;
        const int rq = (u & 3) << 2;
        const int i = __float_as_int(lstage[ci].w);
        *(float4*)&xall[ci][rq] = *(const float4*)&xT[i * 64 + row0 + rq];
    }
    // note: xall is first read only after the barrier below (which drains these writes)

    float acc00 = 0.f, acc01 = 0.f, acc10 = 0.f, acc11 = 0.f;

    for (int cb = 0; cb < n; cb += CH) {
        const int cn = min(CH, n - cb);

        // weight tile: cn*64 exps over 256 threads, all inputs from LDS
        for (int u = tid; u < (cn << 6); u += 256) {
            const int j = u >> 6;
            const int col = u & 63;              // fastest -> conflict-free writes
            const float4 e = lstage[cb + j];
            const float d = (float)(tile0 + col) - e.x;
            wtile[j][col] = e.z * exp2f(e.y * d * d);
        }
        __syncthreads();                 // wtile ready (and, first iter, xall ready)

#pragma unroll 8
        for (int j = 0; j < cn; ++j) {
            const float2 wv = *(const float2*)&wtile[j][cc];       // ds_read_b64
            const float2 xv = *(const float2*)&xall[cb + j][g2];   // ds_read_b64 (broadcast)
            acc00 += wv.x * xv.x;
            acc01 += wv.x * xv.y;
            acc10 += wv.y * xv.x;
            acc11 += wv.y * xv.y;
        }
        __syncthreads();
    }

    // ---- epilogue: + bias, ReLU, contiguous float2 stores ----
    const float b0 = bias[tile0 + cc];
    const float b1 = bias[tile0 + cc + 1];
    const int r0 = row0 + g2;
    float2 v0 = make_float2(fmaxf(acc00 + b0, 0.f), fmaxf(acc10 + b1, 0.f));
    float2 v1 = make_float2(fmaxf(acc01 + b0, 0.f), fmaxf(acc11 + b1, 0.f));
    *(float2*)&out[(size_t)r0 * OUT_F + tile0 + cc]       = v0;
    *(float2*)&out[(size_t)(r0 + 1) * OUT_F + tile0 + cc] = v1;
}

// ---------------- Fallback (ws too small): previous self-contained kernel ----------------
__global__ __launch_bounds__(256, 2) void gauss_fc_kern(
    const float* __restrict__ x, const float* __restrict__ xT,
    const float4* __restrict__ mu4, const float4* __restrict__ sg4,
    const float* __restrict__ amp, const float* __restrict__ bias,
    float* __restrict__ out, const int use_xt) {

    __shared__ float4 list[PASS];
    __shared__ float wtile[CH][64];
    __shared__ float xtile[CH][ROWS];
    __shared__ int   cnt;

    const int tid = threadIdx.x;
    const int cc = (tid & 31) << 1;
    const int g = tid >> 5;
    const int g2 = g << 1;
    const int tile0 = blockIdx.x * TQ;
    const int row0 = blockIdx.y * ROWS;
    const float lo = (float)tile0;
    const float hi = (float)(tile0 + TQ - 1);

    float acc00 = 0.f, acc01 = 0.f, acc10 = 0.f, acc11 = 0.f;

    for (int base = 0; base < IN_F; base += PASS) {
        if (tid == 0) cnt = 0;
        __syncthreads();
        const int q_end = (base + PASS) >> 2;
        for (int q = (base >> 2) + tid; q < q_end; q += 256) {
            const float4 m4 = mu4[q];
            const float4 s4 = sg4[q];
            const float ms[4] = {m4.x, m4.y, m4.z, m4.w};
            const float ss[4] = {s4.x, s4.y, s4.z, s4.w};
#pragma unroll
            for (int e = 0; e < 4; ++e) {
                const float m = ms[e];
                const float s = ss[e];
                const float R = 5.0f * fabsf(s) + 1.0f;
                if (m >= lo - R && m <= hi + R) {
                    const int i = (q << 2) + e;
                    const int p = atomicAdd(&cnt, 1);
                    list[p] = make_float4(m, -0.72134752f / (s * s), amp[i],
                                          __int_as_float(i));
                }
            }
        }
        __syncthreads();
        const int n = cnt;

        for (int cb = 0; cb < n; cb += CH) {
            const int cn = min(CH, n - cb);
            for (int u = tid; u < (cn << 6); u += 256) {
                const int j = u >> 6;
                const int col = u & 63;
                const float4 e = list[cb + j];
                const float d = (float)(tile0 + col) - e.x;
                wtile[j][col] = e.z * exp2f(e.y * d * d);
            }
            {
                const int ci = tid >> 2;
                const int rq = (tid & 3) << 2;
                if (ci < cn) {
                    const int i = __float_as_int(list[cb + ci].w);
                    if (use_xt) {
                        *(float4*)&xtile[ci][rq] = *(const float4*)&xT[i * 64 + row0 + rq];
                    } else {
                        xtile[ci][rq + 0] = x[(size_t)(row0 + rq + 0) * IN_F + i];
                        xtile[ci][rq + 1] = x[(size_t)(row0 + rq + 1) * IN_F + i];
                        xtile[ci][rq + 2] = x[(size_t)(row0 + rq + 2) * IN_F + i];
                        xtile[ci][rq + 3] = x[(size_t)(row0 + rq + 3) * IN_F + i];
                    }
                }
            }
            __syncthreads();
#pragma unroll 8
            for (int j = 0; j < cn; ++j) {
                const float2 wv = *(const float2*)&wtile[j][cc];
                const float2 xv = *(const float2*)&xtile[j][g2];
                acc00 += wv.x * xv.x;
                acc01 += wv.x * xv.y;
                acc10 += wv.y * xv.x;
                acc11 += wv.y * xv.y;
            }
            __syncthreads();
        }
    }

    const float b0 = bias[tile0 + cc];
    const float b1 = bias[tile0 + cc + 1];
    const int r0 = row0 + g2;
    float2 v0 = make_float2(fmaxf(acc00 + b0, 0.f), fmaxf(acc10 + b1, 0.f));
    float2 v1 = make_float2(fmaxf(acc01 + b0, 0.f), fmaxf(acc11 + b1, 0.f));
    *(float2*)&out[(size_t)r0 * OUT_F + tile0 + cc]       = v0;
    *(float2*)&out[(size_t)(r0 + 1) * OUT_F + tile0 + cc] = v1;
}

extern "C" void kernel_launch(void* const* d_in, const int* in_sizes, int n_in,
                              void* d_out, int out_size, void* d_ws, size_t ws_size,
                              hipStream_t stream) {
    const float* x     = (const float*)d_in[0];   // [64, 8192]
    const float* mu    = (const float*)d_in[1];   // [8192]
    const float* sigma = (const float*)d_in[2];   // [8192]
    const float* amp   = (const float*)d_in[3];   // [8192]
    const float* bias  = (const float*)d_in[4];   // [8192]
    float* out = (float*)d_out;

    if (ws_size >= WS_NEEDED) {
        float*  xT   = (float*)d_ws;
        int*    cnt  = (int*)((char*)d_ws + CNT_OFF);
        float4* list = (float4*)((char*)d_ws + LIST_OFF);
        hipMemsetAsync(cnt, 0, NTILE * sizeof(int), stream);
        prep_kern<<<NTILE + IN_F / 256, 256, 0, stream>>>(x, mu, sigma, amp,
                                                          xT, cnt, list);
        dim3 grid(NTILE, BATCH / ROWS);
        gauss_main<<<grid, 256, 0, stream>>>(list, cnt, xT, bias, out);
    } else {
        // self-contained fallback (no workspace): in-kernel scan, direct x reads
        dim3 grid(NTILE, BATCH / ROWS);
        gauss_fc_kern<<<grid, 256, 0, stream>>>(x, nullptr,
                                                (const float4*)mu, (const float4*)sigma,
                                                amp, bias, out, 0);
    }
}

// Round 2
// 81.207 us; speedup vs baseline: 1.1750x; 1.1750x over previous
//
#include <hip/hip_runtime.h>

#define IN_F 8192
#define OUT_F 8192
#define BATCH 64
#define TQ 64                   // output columns per tile
#define NTILE (OUT_F / TQ)      // 128 tiles
#define ROWS 32                 // batch rows per block (grid.y = 2)
#define PASS 2048               // feature-scan pass; PASS/4 == 512 == blockDim -> 1 iter/thread
#define CH 64                   // entries per weight-tile chunk
#define NT 512                  // threads per block

// Single fused kernel: scan + compact + weight-gen + banded FC.
// grid = (128, 2) = 256 blocks -> exactly 1 block/CU, 8 waves/CU (2/SIMD).
// vs round-0: scan & exp redundancy halved (2 row-blocks instead of 4), and the
// transpose/prep/memset dispatches are gone entirely (1 dispatch total).
// LDS: list 32 KB + wtile 16 KB + xtile 8 KB = 56 KB (< 64 KB static limit).
__global__ __launch_bounds__(NT, 2) void gauss_fused(
    const float* __restrict__ x,
    const float4* __restrict__ mu4, const float4* __restrict__ sg4,
    const float* __restrict__ amp, const float* __restrict__ bias,
    float* __restrict__ out) {

    __shared__ float4 list[PASS];        // {mu, kl, amp, idx_bits}  32 KB; cap==PASS => no overflow
    __shared__ float  wtile[CH][64];     // weights per (entry, col) 16 KB
    __shared__ float  xtile[CH][ROWS];   // x per (entry, row)        8 KB
    __shared__ int    cnt;

    const int tid = threadIdx.x;
    const int cc = (tid & 31) << 1;      // col-pair base: 0,2,...,62
    const int g2 = (tid >> 5) << 1;      // row-pair base: 0,2,...,30
    const int tile0 = blockIdx.x * TQ;
    const int row0 = blockIdx.y * ROWS;
    const float lo = (float)tile0;
    const float hi = (float)(tile0 + TQ - 1);

    float acc00 = 0.f, acc01 = 0.f, acc10 = 0.f, acc11 = 0.f;

    for (int base = 0; base < IN_F; base += PASS) {
        if (tid == 0) cnt = 0;
        __syncthreads();

        // ---- scan: exactly one float4 of mu and sigma per thread ----
        {
            const int q = (base >> 2) + tid;
            const float4 m4 = mu4[q];
            const float4 s4 = sg4[q];
            const float ms[4] = {m4.x, m4.y, m4.z, m4.w};
            const float ss[4] = {s4.x, s4.y, s4.z, s4.w};
#pragma unroll
            for (int e = 0; e < 4; ++e) {
                const float m = ms[e];
                const float s = ss[e];
                // R = 5σ+1: dropped-tail absmax ~3e-5 << threshold
                const float R = 5.0f * fabsf(s) + 1.0f;
                if (m >= lo - R && m <= hi + R) {
                    const int i = (q << 2) + e;
                    const int p = atomicAdd(&cnt, 1);     // p < PASS guaranteed
                    // kl = -log2(e)/(2 s^2): w = a * exp2(kl * d^2)
                    list[p] = make_float4(m, -0.72134752f / (s * s), amp[i],
                                          __int_as_float(i));
                }
            }
        }
        __syncthreads();
        const int n = cnt;

        // ---- chunks: weight tile + x gather, then pure-FMA loop ----
        for (int cb = 0; cb < n; cb += CH) {
            const int cn = min(CH, n - cb);

            // weight tile: cn*64 exps over 512 threads (exp2f -> single v_exp_f32)
            for (int u = tid; u < (cn << 6); u += NT) {
                const int j = u >> 6;
                const int col = u & 63;              // fastest -> conflict-free writes
                const float4 e = list[cb + j];
                const float d = (float)(tile0 + col) - e.x;
                wtile[j][col] = e.z * exp2f(e.y * d * d);
            }
            // x gather: direct scattered 4B loads (x is L2/L3-resident, 2 MiB)
            for (int u = tid; u < (cn << 5); u += NT) {
                const int ci = u >> 5;
                const int r = u & 31;                // fastest -> 2-way LDS write (free)
                const int i = __float_as_int(list[cb + ci].w);
                xtile[ci][r] = x[(size_t)(row0 + r) * IN_F + i];
            }
            __syncthreads();

#pragma unroll 8
            for (int j = 0; j < cn; ++j) {
                const float2 wv = *(const float2*)&wtile[j][cc];   // ds_read_b64, 2-way bcast
                const float2 xv = *(const float2*)&xtile[j][g2];   // ds_read_b64, bcast
                acc00 += wv.x * xv.x;
                acc01 += wv.x * xv.y;
                acc10 += wv.y * xv.x;
                acc11 += wv.y * xv.y;
            }
            __syncthreads();
        }
    }

    // ---- epilogue: + bias, ReLU, contiguous float2 stores ----
    const float b0 = bias[tile0 + cc];
    const float b1 = bias[tile0 + cc + 1];
    const int r0 = row0 + g2;
    float2 v0 = make_float2(fmaxf(acc00 + b0, 0.f), fmaxf(acc10 + b1, 0.f));
    float2 v1 = make_float2(fmaxf(acc01 + b0, 0.f), fmaxf(acc11 + b1, 0.f));
    *(float2*)&out[(size_t)r0 * OUT_F + tile0 + cc]       = v0;
    *(float2*)&out[(size_t)(r0 + 1) * OUT_F + tile0 + cc] = v1;
}

extern "C" void kernel_launch(void* const* d_in, const int* in_sizes, int n_in,
                              void* d_out, int out_size, void* d_ws, size_t ws_size,
                              hipStream_t stream) {
    const float* x     = (const float*)d_in[0];   // [64, 8192]
    const float* mu    = (const float*)d_in[1];   // [8192]
    const float* sigma = (const float*)d_in[2];   // [8192]
    const float* amp   = (const float*)d_in[3];   // [8192]
    const float* bias  = (const float*)d_in[4];   // [8192]
    float* out = (float*)d_out;
    (void)d_ws; (void)ws_size;                    // workspace intentionally unused

    dim3 grid(NTILE, BATCH / ROWS);               // (128, 2) = 256 blocks
    gauss_fused<<<grid, NT, 0, stream>>>(x, (const float4*)mu, (const float4*)sigma,
                                         amp, bias, out);
}